// Round 6
// baseline (244.106 us; speedup 1.0000x reference)
//
#include <hip/hip_runtime.h>
#include <hip/hip_bf16.h>

// Workspace layout (needs 34 MB):
//   [0, 2MB)    Ut : U^T as bf16, Ut[n][k] = bf16(U[k][n])
//   [2MB, 34MB) xg : gathered x as bf16, xg[b][i] = bf16(x[b][ans[b][i]])
#define WS_UT    ((size_t)0)
#define WS_XG    ((size_t)2*1024*1024)

typedef __attribute__((ext_vector_type(8))) short short8;
typedef __attribute__((ext_vector_type(4))) float floatx4;

__device__ __forceinline__ unsigned short f2bf(float f) {
  __hip_bfloat16 h = __float2bfloat16(f);
  return __builtin_bit_cast(unsigned short, h);
}
__device__ __forceinline__ float bf2f(unsigned short u) {
  return __uint_as_float(((unsigned)u) << 16);
}

// ---------------- K1: prep (Ut = bf16(U^T)) + gather (xg) in one launch ----------------
// blocks [0,256): transpose+cast U.  blocks [256, 256+4096): per-row LDS gather of x.
__global__ void __launch_bounds__(256) prep_gather_k(const float* __restrict__ U,
                                                     const float* __restrict__ x,
                                                     const int* __restrict__ perm,
                                                     const int* __restrict__ prand,
                                                     unsigned short* __restrict__ ut,
                                                     unsigned short* __restrict__ xg) {
  __shared__ __align__(16) char smem[64 * 65 * 4];  // union: tile[64][65] f32 / xrow[4][1024] f32
  if (blockIdx.x < 256) {
    float (*tile)[65] = (float (*)[65])smem;
    const int tn = (blockIdx.x & 15) * 64;
    const int tk = (blockIdx.x >> 4) * 64;
    const int r = threadIdx.x >> 6;
    const int c = threadIdx.x & 63;
    for (int s = 0; s < 16; ++s)
      tile[s * 4 + r][c] = U[(size_t)(tk + s * 4 + r) * 1024 + tn + c];
    __syncthreads();
    for (int s = 0; s < 16; ++s)
      ut[(size_t)(tn + s * 4 + r) * 1024 + tk + c] = f2bf(tile[c][s * 4 + r]);
    return;
  }
  float (*xrow)[1024] = (float (*)[1024])smem;
  const int w = threadIdx.x >> 6, lane = threadIdx.x & 63;
  const int row = (blockIdx.x - 256) * 4 + w;
  const unsigned mult = ((unsigned)prand[0] * 6u) & 1023u;
  const unsigned br = (((unsigned)row & 1023u) * mult + 1u) & 1023u;
  const float* xr = x + (size_t)row * 1024;
  unsigned short* xo = xg + (size_t)row * 1024;
  for (int t = 0; t < 4; ++t) {
    floatx4 v = *(const floatx4*)(xr + t * 256 + lane * 4);
    *(floatx4*)(&xrow[w][t * 256 + lane * 4]) = v;
  }
  __syncthreads();
  for (int t = 0; t < 4; ++t) {
    int i0 = t * 256 + lane * 4;
    int4 p = *(const int4*)(perm + i0);
    ushort4 o;
    o.x = f2bf(xrow[w][((unsigned)p.x * br) & 1023u]);
    o.y = f2bf(xrow[w][((unsigned)p.y * br) & 1023u]);
    o.z = f2bf(xrow[w][((unsigned)p.z * br) & 1023u]);
    o.w = f2bf(xrow[w][((unsigned)p.w * br) & 1023u]);
    *(ushort4*)(xo + i0) = o;
  }
}

// ---------------- K2: fused GEMM + scatter + residual ----------------
// Round-6 redesign: BARRIER-FREE, LDS-FREE K-loop.
// R4 (single-buf LDS) and R5 (double-buf + counted vmcnt) both landed 65-72us
// -- 3-4x above all floors -- implicating the global_load_lds->barrier->
// ds_read chain itself (LDS-write delivery + 64 barrier quanta at 2 waves/
// SIMD), not the schedule around it.
// New structure: 1024 threads (16 waves = 4 waves/SIMD), tile M=64 x N=1024,
// grid 256 (1 block/CU). Wave w owns cols [w*64, w*64+64):
//  * B (ut): every element consumed by exactly ONE wave once -> stream
//    L2->VGPR directly. No sharing -> no LDS -> no barriers.
//  * A (xg): each wave loads its own fragments; the 4KB half-step A slice is
//    L1-resident so the 16x cross-wave reuse hits L1.
//  * acc 64 f32/thread (4 row-grps x 4 col-grps) -> 128-reg budget fits at
//    4 waves/SIMD; TLP + full unroll hides L2 latency (this is what R2/R3's
//    2-wave/128-reg version fatally lacked).
//  * Addressing built for SGPR-base + VGPR-offset form: 8 uniform bases
//    (SGPRs), one 32-bit lane offset for A and B, k folds into the 13-bit
//    immediate -> ~4 address VGPRs, zero per-iteration address math.
//  * LDS (64KB sbuf) + barriers used ONLY in the scatter epilogue.
__global__ void __launch_bounds__(1024) gemm_scatter_k(
    const unsigned short* __restrict__ xg,
    const unsigned short* __restrict__ ut,
    const int* __restrict__ perm,
    const int* __restrict__ prand,
    float* __restrict__ out) {
  __shared__ __align__(16) float sbuf[16 * 1024];  // epilogue scatter buffer
  const int tid = threadIdx.x;
  const int w = tid >> 6, lane = tid & 63;
  const int m = lane & 15, q = lane >> 4;
  const int R0 = blockIdx.x * 64;
  const int wn = w * 64;

  // uniform (SGPR) base pointers; per-lane 32-bit element offsets
  const unsigned short* ua[4];
  const unsigned short* ub[4];
#pragma unroll
  for (int i = 0; i < 4; ++i) ua[i] = xg + (size_t)(R0 + i * 16) * 1024;
#pragma unroll
  for (int jj = 0; jj < 4; ++jj) ub[jj] = ut + (size_t)jj * 16 * 1024;
  const int va = m * 1024 + q * 8;             // A: row m (of 16-grp), k-chunk q
  const int vb = (wn + m) * 1024 + q * 8;      // B: col wn+m, k-chunk q

  floatx4 acc[4][4];
#pragma unroll
  for (int i = 0; i < 4; ++i)
#pragma unroll
    for (int jj = 0; jj < 4; ++jj) acc[i][jj] = (floatx4)0.0f;

#pragma unroll
  for (int kt = 0; kt < 16; ++kt) {
#pragma unroll
    for (int s = 0; s < 2; ++s) {
      const int kp = kt * 64 + s * 32;  // folds into load immediate
      short8 b[4], a[4];
#pragma unroll
      for (int jj = 0; jj < 4; ++jj)
        b[jj] = *(const short8*)(ub[jj] + vb + kp);
#pragma unroll
      for (int i = 0; i < 4; ++i)
        a[i] = *(const short8*)(ua[i] + va + kp);
#pragma unroll
      for (int i = 0; i < 4; ++i)
#pragma unroll
        for (int jj = 0; jj < 4; ++jj)
          acc[i][jj] = __builtin_amdgcn_mfma_f32_16x16x32_bf16(b[jj], a[i],
                                                               acc[i][jj], 0, 0, 0);
    }
  }

  // ---- epilogue: 4 passes of 16 rows; value = rs*y + xg scattered via LDS ----
  // Swapped-mfma layout (same convention as passing R5 kernel):
  //   lane(m,q) holds y[R0 + i*16 + m][wn + jj*16 + q*4 + r], r=0..3.
  // Each pass covers all 16384 sbuf slots exactly once across the 16 waves
  // (disjoint j-sets -> disjoint scatter targets; per-row perm bijective),
  // so the only syncs needed are scatter->store and store->next-scatter.
  const unsigned mult = ((unsigned)prand[0] * 6u) & 1023u;
  const float rs = 0.33333334f;  // sqrt(0.1/0.9) = 1/3
#pragma unroll
  for (int i = 0; i < 4; ++i) {
    const int row = R0 + i * 16 + m;
    const unsigned br = (((unsigned)row & 1023u) * mult + 1u) & 1023u;
    const unsigned short* xr = xg + (size_t)row * 1024;
#pragma unroll
    for (int jj = 0; jj < 4; ++jj) {
      const int j0 = wn + jj * 16 + q * 4;  // 4 consecutive y-cols per lane
      const int4 p4 = *(const int4*)(perm + j0);
      const ushort4 x4 = *(const ushort4*)(xr + j0);  // L2-hot (block's A panel)
      sbuf[m * 1024 + (((unsigned)p4.x * br) & 1023u)] = rs * acc[i][jj][0] + bf2f(x4.x);
      sbuf[m * 1024 + (((unsigned)p4.y * br) & 1023u)] = rs * acc[i][jj][1] + bf2f(x4.y);
      sbuf[m * 1024 + (((unsigned)p4.z * br) & 1023u)] = rs * acc[i][jj][2] + bf2f(x4.z);
      sbuf[m * 1024 + (((unsigned)p4.w * br) & 1023u)] = rs * acc[i][jj][3] + bf2f(x4.w);
    }
    __syncthreads();
    float* orow0 = out + (size_t)(R0 + i * 16) * 1024;
#pragma unroll
    for (int v = 0; v < 4; ++v) {
      const int f = v * 1024 + tid;  // float4 index in [0,4096)
      *(floatx4*)(orow0 + ((f >> 8) * 1024 + (f & 255) * 4)) =
          *(const floatx4*)(sbuf + (size_t)f * 4);
    }
    if (i < 3) __syncthreads();
  }
}

extern "C" void kernel_launch(void* const* d_in, const int* in_sizes, int n_in,
                              void* d_out, int out_size, void* d_ws, size_t ws_size,
                              hipStream_t stream) {
  const float* x = (const float*)d_in[0];
  const float* U = (const float*)d_in[1];
  const int* perm = (const int*)d_in[2];
  const int* prand = (const int*)d_in[3];
  float* out = (float*)d_out;
  char* ws = (char*)d_ws;
  unsigned short* ut = (unsigned short*)(ws + WS_UT);
  unsigned short* xg = (unsigned short*)(ws + WS_XG);

  prep_gather_k<<<256 + 4096, 256, 0, stream>>>(U, x, perm, prand, ut, xg);
  gemm_scatter_k<<<256, 1024, 0, stream>>>(xg, ut, perm, prand, out);
}

// Round 7
// 165.680 us; speedup vs baseline: 1.4734x; 1.4734x over previous
//
#include <hip/hip_runtime.h>
#include <hip/hip_bf16.h>

// Workspace layout (needs 34 MB):
//   [0, 2MB)    Ut : U^T as bf16, Ut[n][k] = bf16(U[k][n])
//   [2MB, 34MB) xg : gathered x as bf16, xg[b][i] = bf16(x[b][ans[b][i]])
#define WS_UT    ((size_t)0)
#define WS_XG    ((size_t)2*1024*1024)

typedef __attribute__((ext_vector_type(8))) short short8;
typedef __attribute__((ext_vector_type(4))) float floatx4;

__device__ __forceinline__ void load_lds16(const void* g, void* l) {
  __builtin_amdgcn_global_load_lds(
      (const __attribute__((address_space(1))) void*)g,
      (__attribute__((address_space(3))) void*)l, 16, 0, 0);
}

__device__ __forceinline__ unsigned short f2bf(float f) {
  __hip_bfloat16 h = __float2bfloat16(f);
  return __builtin_bit_cast(unsigned short, h);
}
__device__ __forceinline__ float bf2f(unsigned short u) {
  return __uint_as_float(((unsigned)u) << 16);
}

// ---------------- K1: prep (Ut = bf16(U^T)) + gather (xg) in one launch ----------------
__global__ void __launch_bounds__(256) prep_gather_k(const float* __restrict__ U,
                                                     const float* __restrict__ x,
                                                     const int* __restrict__ perm,
                                                     const int* __restrict__ prand,
                                                     unsigned short* __restrict__ ut,
                                                     unsigned short* __restrict__ xg) {
  __shared__ __align__(16) char smem[64 * 65 * 4];
  if (blockIdx.x < 256) {
    float (*tile)[65] = (float (*)[65])smem;
    const int tn = (blockIdx.x & 15) * 64;
    const int tk = (blockIdx.x >> 4) * 64;
    const int r = threadIdx.x >> 6;
    const int c = threadIdx.x & 63;
    for (int s = 0; s < 16; ++s)
      tile[s * 4 + r][c] = U[(size_t)(tk + s * 4 + r) * 1024 + tn + c];
    __syncthreads();
    for (int s = 0; s < 16; ++s)
      ut[(size_t)(tn + s * 4 + r) * 1024 + tk + c] = f2bf(tile[c][s * 4 + r]);
    return;
  }
  float (*xrow)[1024] = (float (*)[1024])smem;
  const int w = threadIdx.x >> 6, lane = threadIdx.x & 63;
  const int row = (blockIdx.x - 256) * 4 + w;
  const unsigned mult = ((unsigned)prand[0] * 6u) & 1023u;
  const unsigned br = (((unsigned)row & 1023u) * mult + 1u) & 1023u;
  const float* xr = x + (size_t)row * 1024;
  unsigned short* xo = xg + (size_t)row * 1024;
  for (int t = 0; t < 4; ++t) {
    floatx4 v = *(const floatx4*)(xr + t * 256 + lane * 4);
    *(floatx4*)(&xrow[w][t * 256 + lane * 4]) = v;
  }
  __syncthreads();
  for (int t = 0; t < 4; ++t) {
    int i0 = t * 256 + lane * 4;
    int4 p = *(const int4*)(perm + i0);
    ushort4 o;
    o.x = f2bf(xrow[w][((unsigned)p.x * br) & 1023u]);
    o.y = f2bf(xrow[w][((unsigned)p.y * br) & 1023u]);
    o.z = f2bf(xrow[w][((unsigned)p.z * br) & 1023u]);
    o.w = f2bf(xrow[w][((unsigned)p.w * br) & 1023u]);
    *(ushort4*)(xo + i0) = o;
  }
}

// ---------------- K2: fused GEMM + scatter, wave-local B pipeline ----------------
// M=64 x N=1024, grid 256 (1 block/CU), 512 threads (8 waves; 2 waves/SIMD ->
// 256 unified regs/wave, the ONLY budget where acc(128)+frags fits; 16-wave
// configs cap at 128 regs/wave -> R6's forced serialization).
// Structural insight: wave w stages AND consumes only ut rows [w*128,+128) ->
// B is WAVE-LOCAL. Barriers exist only for the 8KB A tile.
//  * B: per-wave single-buffered 16KB LDS slice; protected by wave program
//    order + counted vmcnt, NO barrier. Staged 1 step ahead -> delivery
//    (~2340cy) overlaps the ~2600cy compute step.
//  * A: triple-buffered 3x8KB so stage A(k+2) (pre-barrier) can never race
//    readers of A(k).
//  * Per step: [vmcnt(1) drain B(k)] frags+MFMA -> lgkmcnt(0) ->
//    stage B(k+1)+A(k+2) -> vmcnt(17) (retires A(k+1) ONLY; B(k+1) stays in
//    flight across the barrier) -> raw s_barrier. 1 barrier/step (R5 had 4).
//  * LDS 152KB dynamic: A 3x8KB [0,24K) + B 8x16KB [24K,152K).
__global__ void __launch_bounds__(512, 2) gemm_scatter_k(
    const unsigned short* __restrict__ xg,
    const unsigned short* __restrict__ ut,
    const int* __restrict__ perm,
    const int* __restrict__ prand,
    float* __restrict__ out) {
  extern __shared__ __align__(16) char smem[];
  const int tid = threadIdx.x;
  const int w = tid >> 6, lane = tid & 63;
  const int m = lane & 15, q = lane >> 4;
  const int R0 = blockIdx.x * 64;
  const int wn = w * 128;

  // fragment read swizzle: logical chunk s*4+q lives at slot (s*4+q)^(row&7),
  // row&7 == m&7 for both A (row=i*16+m) and B (row_l=jj*16+m).
  const int swz0 = (q ^ (m & 7)) * 16;
  const int vA0 = m * 128 + swz0;          // + (kt%3)*8192 + i*2048 (imm)
  const int vA1 = vA0 ^ 64;                // s=1
  const int vB0 = 24576 + w * 16384 + m * 128 + swz0;  // + jj*2048 (imm)
  const int vB1 = vB0 ^ 64;

  // staging addresses (linear LDS dest, inverse-swizzled global source)
  // A: thread covers row=tid>>3, slot=tid&7 (1 instr/wave, 8KB/block)
  const unsigned short* asrc =
      xg + (size_t)(R0 + (tid >> 3)) * 1024 + (size_t)(((tid & 7) ^ ((tid >> 3) & 7)) * 8);
  // B: wave w rows [wn, wn+128), 16 instr: row_l = t*8 + (lane>>3)
  const unsigned short* bsrc0 =
      ut + (size_t)(wn + (lane >> 3)) * 1024 + (size_t)(((lane & 7) ^ (lane >> 3)) * 8);
  char* bdst0 = smem + 24576 + w * 16384 + lane * 16;

  floatx4 acc[4][8];
#pragma unroll
  for (int i = 0; i < 4; ++i)
#pragma unroll
    for (int jj = 0; jj < 8; ++jj) acc[i][jj] = (floatx4)0.0f;

  // ---- prologue: A(0), B(0), A(1); drain A0+B0, keep A1 in flight ----
  load_lds16(asrc, smem + tid * 16);                       // A(0) -> buf0
#pragma unroll
  for (int t = 0; t < 16; ++t)                             // B(0)
    load_lds16(bsrc0 + (size_t)t * 8192, bdst0 + t * 1024);
  load_lds16(asrc + 64, smem + 8192 + tid * 16);           // A(1) -> buf1
  asm volatile("s_waitcnt vmcnt(1)" ::: "memory");
  __builtin_amdgcn_sched_barrier(0);
  __builtin_amdgcn_s_barrier();
  __builtin_amdgcn_sched_barrier(0);

#pragma unroll
  for (int kt = 0; kt < 16; ++kt) {
    const int ab = (kt % 3) * 8192;
    // s=0 A frags (A(kt) ready via barrier)
    short8 a0[4];
#pragma unroll
    for (int i = 0; i < 4; ++i)
      a0[i] = *(const short8*)(smem + ab + i * 2048 + vA0);
    if (kt > 0) {  // drain B(kt); keep A(kt+1) in flight
      asm volatile("s_waitcnt vmcnt(1)" ::: "memory");
      __builtin_amdgcn_sched_barrier(0);
    }
    __builtin_amdgcn_s_setprio(1);
#pragma unroll
    for (int jj = 0; jj < 8; ++jj) {
      short8 b = *(const short8*)(smem + jj * 2048 + vB0);
#pragma unroll
      for (int i = 0; i < 4; ++i)
        acc[i][jj] = __builtin_amdgcn_mfma_f32_16x16x32_bf16(b, a0[i], acc[i][jj], 0, 0, 0);
    }
    // s=1
    short8 a1[4];
#pragma unroll
    for (int i = 0; i < 4; ++i)
      a1[i] = *(const short8*)(smem + ab + i * 2048 + vA1);
#pragma unroll
    for (int jj = 0; jj < 8; ++jj) {
      short8 b = *(const short8*)(smem + jj * 2048 + vB1);
#pragma unroll
      for (int i = 0; i < 4; ++i)
        acc[i][jj] = __builtin_amdgcn_mfma_f32_16x16x32_bf16(b, a1[i], acc[i][jj], 0, 0, 0);
    }
    __builtin_amdgcn_s_setprio(0);
    if (kt < 15) {
      // all our ds_reads of B(kt)/A(kt) must COMPLETE before restaging lands
      asm volatile("s_waitcnt lgkmcnt(0)" ::: "memory");
      __builtin_amdgcn_sched_barrier(0);
      const int k1 = (kt + 1) * 64;
#pragma unroll
      for (int t = 0; t < 16; ++t)                          // B(kt+1)
        load_lds16(bsrc0 + (size_t)t * 8192 + k1, bdst0 + t * 1024);
      if (kt < 14)                                          // A(kt+2)
        load_lds16(asrc + (size_t)(kt + 2) * 64, smem + ((kt + 2) % 3) * 8192 + tid * 16);
      // retire A(kt+1) (needed right after barrier); B(kt+1) stays in flight
      if (kt < 14) asm volatile("s_waitcnt vmcnt(17)" ::: "memory");
      else         asm volatile("s_waitcnt vmcnt(16)" ::: "memory");
      __builtin_amdgcn_sched_barrier(0);
      __builtin_amdgcn_s_barrier();
      __builtin_amdgcn_sched_barrier(0);
    }
  }
  __syncthreads();  // full drain; LDS reused as scatter buffer below

  // ---- epilogue: 8 passes of 8 rows; value = rs*y + xg, scatter via LDS ----
  // Mapping (verified R4-R6): acc[i][jj][r] = y[R0+i*16+m][wn+jj*16+q*4+r].
  const unsigned mult = ((unsigned)prand[0] * 6u) & 1023u;
  const float rs = 0.33333334f;  // sqrt(0.1/0.9) = 1/3
  float* sbuf = (float*)(smem + 24576);  // [8][1024] f32 = 32KB
#pragma unroll
  for (int p = 0; p < 8; ++p) {
    const int i = p >> 1;
    if ((m >> 3) == (p & 1)) {  // lane's rows i*16+m fall in [p*8, p*8+8)
      const int r = i * 16 + m;
      const unsigned br = (((unsigned)(R0 + r) & 1023u) * mult + 1u) & 1023u;
      const unsigned short* xr = xg + (size_t)(R0 + r) * 1024;
#pragma unroll
      for (int jj = 0; jj < 8; ++jj) {
        const int j0 = wn + jj * 16 + q * 4;
        const int4 p4 = *(const int4*)(perm + j0);
        const ushort4 x4 = *(const ushort4*)(xr + j0);
        sbuf[((r & 7) << 10) + (((unsigned)p4.x * br) & 1023u)] = rs * acc[i][jj][0] + bf2f(x4.x);
        sbuf[((r & 7) << 10) + (((unsigned)p4.y * br) & 1023u)] = rs * acc[i][jj][1] + bf2f(x4.y);
        sbuf[((r & 7) << 10) + (((unsigned)p4.z * br) & 1023u)] = rs * acc[i][jj][2] + bf2f(x4.z);
        sbuf[((r & 7) << 10) + (((unsigned)p4.w * br) & 1023u)] = rs * acc[i][jj][3] + bf2f(x4.w);
      }
    }
    __syncthreads();
    float* orow = out + (size_t)(R0 + p * 8) * 1024;
#pragma unroll
    for (int v = 0; v < 4; ++v) {
      const int f = v * 512 + tid;  // float4 idx in [0,2048)
      *(floatx4*)(orow + (size_t)f * 4) = *(const floatx4*)(sbuf + (size_t)f * 4);
    }
    if (p < 7) __syncthreads();
  }
}

extern "C" void kernel_launch(void* const* d_in, const int* in_sizes, int n_in,
                              void* d_out, int out_size, void* d_ws, size_t ws_size,
                              hipStream_t stream) {
  const float* x = (const float*)d_in[0];
  const float* U = (const float*)d_in[1];
  const int* perm = (const int*)d_in[2];
  const int* prand = (const int*)d_in[3];
  float* out = (float*)d_out;
  char* ws = (char*)d_ws;
  unsigned short* ut = (unsigned short*)(ws + WS_UT);
  unsigned short* xg = (unsigned short*)(ws + WS_XG);

  // 152KB dynamic LDS for K2
  hipFuncSetAttribute((const void*)gemm_scatter_k,
                      hipFuncAttributeMaxDynamicSharedMemorySize, 155648);

  prep_gather_k<<<256 + 4096, 256, 0, stream>>>(U, x, perm, prand, ut, xg);
  gemm_scatter_k<<<256, 512, 155648, stream>>>(xg, ut, perm, prand, out);
}